// Round 1
// baseline (5785.604 us; speedup 1.0000x reference)
//
#include <hip/hip_runtime.h>

// SentimentLSTM: B=64, T=512, E=128, H=256, V=100000, O=1
// outputs: sig_out[64], hT[1,64,256], cT[1,64,256] -> 32832 f32
//
// ws layout:
//   gx   bf16 [T][B][4H]      67,108,864 B
//   hs   f32  [T+1][B][H]     33,619,968 B
//   part f32  [64][8]         (4 KB slot)
//   cnt  u32  [groups]        (256 B)
// total ~100.7 MB

#define BATCH 64
#define TSTEPS 512
#define EDIM 128
#define HDIM 256
#define G4H 1024

typedef short bf16x8 __attribute__((ext_vector_type(8)));
typedef short bf16x4 __attribute__((ext_vector_type(4)));
typedef float f32x4 __attribute__((ext_vector_type(4)));

__device__ __forceinline__ unsigned short f2bf(float f) {
  unsigned u = __builtin_bit_cast(unsigned, f);
  return (unsigned short)((u + 0x7fffu + ((u >> 16) & 1u)) >> 16);
}
__device__ __forceinline__ float bf2f(unsigned short h) {
  unsigned u = ((unsigned)h) << 16;
  return __builtin_bit_cast(float, u);
}
__device__ __forceinline__ unsigned pk2(float a, float b) {
  return (unsigned)f2bf(a) | ((unsigned)f2bf(b) << 16);
}
__device__ __forceinline__ float fsig(float x) {
  return __builtin_amdgcn_rcpf(1.f + __expf(-x));
}
__device__ __forceinline__ float ftanh(float x) {
  return 1.f - 2.f * __builtin_amdgcn_rcpf(__expf(2.f * x) + 1.f);
}
// Load an 8-elem bf16 fragment: elems 0-3 at k0, elems 4-7 at k0+16.
// Same recipe used for A and B everywhere -> k-permutation cancels.
__device__ __forceinline__ bf16x8 ldfrag(const unsigned short* p) {
  bf16x4 a = *(const bf16x4*)p;
  bf16x4 b = *(const bf16x4*)(p + 16);
  return __builtin_shufflevector(a, b, 0, 1, 2, 3, 4, 5, 6, 7);
}

// ---------------- K1: gx[t][b][g] = emb[x[b,t]] @ W_ih^T + b_ih  (bf16 out) --
__global__ __launch_bounds__(256) void k_gx(const int* __restrict__ x,
                                            const float* __restrict__ emb,
                                            const float* __restrict__ Wih,
                                            const float* __restrict__ bih,
                                            unsigned short* __restrict__ gx) {
  const int t = blockIdx.x;        // 0..511 (one t = all 64 batches = M tile)
  const int g0 = blockIdx.y * 64;  // gate-col tile
  const int tid = threadIdx.x;
  __shared__ unsigned short Al[64 * 136];  // emb rows, bf16, padded stride
  __shared__ unsigned short Bl[64 * 136];  // W_ih rows, bf16
  __shared__ int tok[64];
  if (tid < 64) tok[tid] = x[tid * TSTEPS + t];  // x[b][t]
  __syncthreads();
  {
    const int r = tid >> 2, c0 = (tid & 3) * 32;
    const float* asrc = emb + (size_t)tok[r] * EDIM + c0;
    const float* bsrc = Wih + (size_t)(g0 + r) * EDIM + c0;
#pragma unroll
    for (int s = 0; s < 32; s += 8) {
      float4 a0 = *(const float4*)(asrc + s);
      float4 a1 = *(const float4*)(asrc + s + 4);
      uint4 pa = {pk2(a0.x, a0.y), pk2(a0.z, a0.w), pk2(a1.x, a1.y), pk2(a1.z, a1.w)};
      *(uint4*)&Al[r * 136 + c0 + s] = pa;
      float4 b0 = *(const float4*)(bsrc + s);
      float4 b1 = *(const float4*)(bsrc + s + 4);
      uint4 pb = {pk2(b0.x, b0.y), pk2(b0.z, b0.w), pk2(b1.x, b1.y), pk2(b1.z, b1.w)};
      *(uint4*)&Bl[r * 136 + c0 + s] = pb;
    }
  }
  __syncthreads();
  const int lane = tid & 63, w = tid >> 6;
  const int lo = lane & 15, hi = lane >> 4;
  const int mb = (w & 1) * 32, nb = (w >> 1) * 32;
  f32x4 acc[2][2];
#pragma unroll
  for (int j = 0; j < 2; ++j) {
    float bv = bih[g0 + nb + j * 16 + lo];
    acc[0][j] = (f32x4){bv, bv, bv, bv};
    acc[1][j] = acc[0][j];
  }
#pragma unroll
  for (int kk = 0; kk < 4; ++kk) {
    bf16x8 af0 = ldfrag(&Al[(mb + lo) * 136 + kk * 32 + hi * 4]);
    bf16x8 af1 = ldfrag(&Al[(mb + 16 + lo) * 136 + kk * 32 + hi * 4]);
    bf16x8 bf0 = ldfrag(&Bl[(nb + lo) * 136 + kk * 32 + hi * 4]);
    bf16x8 bf1 = ldfrag(&Bl[(nb + 16 + lo) * 136 + kk * 32 + hi * 4]);
    acc[0][0] = __builtin_amdgcn_mfma_f32_16x16x32_bf16(af0, bf0, acc[0][0], 0, 0, 0);
    acc[0][1] = __builtin_amdgcn_mfma_f32_16x16x32_bf16(af0, bf1, acc[0][1], 0, 0, 0);
    acc[1][0] = __builtin_amdgcn_mfma_f32_16x16x32_bf16(af1, bf0, acc[1][0], 0, 0, 0);
    acc[1][1] = __builtin_amdgcn_mfma_f32_16x16x32_bf16(af1, bf1, acc[1][1], 0, 0, 0);
  }
#pragma unroll
  for (int i = 0; i < 2; ++i)
#pragma unroll
    for (int j = 0; j < 2; ++j)
#pragma unroll
      for (int r = 0; r < 4; ++r) {
        int m = mb + i * 16 + hi * 4 + r;     // batch (C row)
        int col = g0 + nb + j * 16 + lo;      // gate col (C col)
        gx[(size_t)(t * BATCH + m) * G4H + col] = f2bf(acc[i][j][r]);
      }
}

// ---------------- K2: the LSTM recurrence ----------------------------------
// 4 groups x 16 batches; each group = 8 blocks, block owns 32 hidden units
// (128 W_hh rows) held as persistent bf16 MFMA B-fragments in VGPRs.
// Per step: gates = gx + b_hh + h @ W_slice^T (8x mfma 16x16x32), cell update,
// publish h-slice to hs[t+1], flag-sync group, restage full h into LDS.
__global__ __launch_bounds__(512) void k_rec(const unsigned short* __restrict__ gx,
                                             const float* __restrict__ Whh,
                                             const float* __restrict__ bhh,
                                             float* __restrict__ hs,
                                             unsigned* __restrict__ cnt,
                                             float* __restrict__ out) {
  const int tid = threadIdx.x;
  const int grp = blockIdx.x >> 3, p = blockIdx.x & 7;
  const int b0 = grp * 16, j0 = p * 32;
  const int lane = tid & 63, w = tid >> 6;
  const int lo = lane & 15, hi = lane >> 4;
  const int gate = w >> 1, jw = (w & 1) * 16;
  const int grow = gate * HDIM + j0 + jw + lo;  // this lane's W_hh row (= C col)
  __shared__ unsigned short h_lds[16 * 264];    // [16 batch][256 k] bf16, pad 8
  __shared__ unsigned short gx_lds[2][16 * 128];// dbuf [16 batch][4g x 32u] bf16
  __shared__ float g_lds[4][32][17];            // [gate][unit][batch] pad
  // persistent W fragments (one-time load, f32 -> bf16)
  bf16x8 wf[8];
#pragma unroll
  for (int kk = 0; kk < 8; ++kk) {
    const float* wsrc = Whh + (size_t)grow * HDIM + kk * 32 + hi * 4;
    float4 v0 = *(const float4*)wsrc;
    float4 v1 = *(const float4*)(wsrc + 16);
    bf16x8 f;
    f[0] = (short)f2bf(v0.x); f[1] = (short)f2bf(v0.y);
    f[2] = (short)f2bf(v0.z); f[3] = (short)f2bf(v0.w);
    f[4] = (short)f2bf(v1.x); f[5] = (short)f2bf(v1.y);
    f[6] = (short)f2bf(v1.z); f[7] = (short)f2bf(v1.w);
    wf[kk] = f;
  }
  const float bhv = bhh[grow];
  const int ub = tid >> 5, uu = tid & 31;  // update-phase (batch, unit)
  float c_reg = 0.f;
  // initial stage: gx[0] and h^(0)=0 (hs[0] memset by host)
  {
    if (tid < 256) {
      const int fb = tid >> 4, fg = (tid >> 2) & 3, fq = tid & 3;
      uint4 v = *(const uint4*)(gx + (size_t)(b0 + fb) * G4H + fg * HDIM + j0 + fq * 8);
      *(uint4*)&gx_lds[0][fb * 128 + fg * 32 + fq * 8] = v;
    }
    const int hb = tid >> 5, hc = tid & 31;
    const float* hsrc = hs + (size_t)(b0 + hb) * HDIM + hc * 8;
    float4 v0 = *(const float4*)hsrc;
    float4 v1 = *(const float4*)(hsrc + 4);
    uint4 pk = {pk2(v0.x, v0.y), pk2(v0.z, v0.w), pk2(v1.x, v1.y), pk2(v1.z, v1.w)};
    *(uint4*)&h_lds[hb * 264 + hc * 8] = pk;
  }
  __syncthreads();
  for (int t = 0; t < TSTEPS; ++t) {
    const int pbuf = t & 1;
    // C init = gx + b_hh  (C map: row=batch=(hi*4+r), col=this lane's unit)
    f32x4 acc;
#pragma unroll
    for (int r = 0; r < 4; ++r)
      acc[r] = bf2f(gx_lds[pbuf][(hi * 4 + r) * 128 + gate * 32 + jw + lo]) + bhv;
    // h @ W^T : A row = batch = lo, same k recipe as wf
#pragma unroll
    for (int kk = 0; kk < 8; ++kk) {
      bf16x8 af = ldfrag(&h_lds[lo * 264 + kk * 32 + hi * 4]);
      acc = __builtin_amdgcn_mfma_f32_16x16x32_bf16(af, wf[kk], acc, 0, 0, 0);
    }
#pragma unroll
    for (int r = 0; r < 4; ++r) g_lds[gate][jw + lo][hi * 4 + r] = acc[r];
    __syncthreads();
    // prefetch next gx tile into registers (hidden under update phase)
    uint4 gpre;
    const bool dopf = (t < TSTEPS - 1) && (tid < 256);
    if (dopf) {
      const int fb = tid >> 4, fg = (tid >> 2) & 3, fq = tid & 3;
      gpre = *(const uint4*)(gx + (size_t)(t + 1) * (BATCH * G4H) +
                             (size_t)(b0 + fb) * G4H + fg * HDIM + j0 + fq * 8);
    }
    // cell update (torch gate order i,f,g,o)
    float iv = fsig(g_lds[0][uu][ub]);
    float fv = fsig(g_lds[1][uu][ub]);
    float gv = ftanh(g_lds[2][uu][ub]);
    float ov = fsig(g_lds[3][uu][ub]);
    c_reg = fv * c_reg + iv * gv;
    float hval = ov * ftanh(c_reg);
    hs[(size_t)(t + 1) * (BATCH * HDIM) + (size_t)(b0 + ub) * HDIM + j0 + uu] = hval;
    if (t == TSTEPS - 1) {
      out[64 + (b0 + ub) * HDIM + j0 + uu] = hval;                 // hT
      out[64 + BATCH * HDIM + (b0 + ub) * HDIM + j0 + uu] = c_reg; // cT
    }
    if (dopf) {
      const int fb = tid >> 4, fg = (tid >> 2) & 3, fq = tid & 3;
      *(uint4*)&gx_lds[pbuf ^ 1][fb * 128 + fg * 32 + fq * 8] = gpre;
    }
    if (t == TSTEPS - 1) break;
    // publish + group flag sync (monotonic counter, 2 global buffers never alias)
    __threadfence();
    __syncthreads();
    if (tid == 0) {
      __hip_atomic_fetch_add(&cnt[grp], 1u, __ATOMIC_RELEASE, __HIP_MEMORY_SCOPE_AGENT);
      const unsigned target = 8u * (unsigned)(t + 1);
      while (__hip_atomic_load(&cnt[grp], __ATOMIC_RELAXED, __HIP_MEMORY_SCOPE_AGENT) < target) {}
    }
    __syncthreads();
    __threadfence();  // acquire side: fresh reads of peers' h slices
    {
      const int hb = tid >> 5, hc = tid & 31;
      const float* hsrc = hs + (size_t)(t + 1) * (BATCH * HDIM) +
                          (size_t)(b0 + hb) * HDIM + hc * 8;
      float4 v0 = *(const float4*)hsrc;
      float4 v1 = *(const float4*)(hsrc + 4);
      uint4 pk = {pk2(v0.x, v0.y), pk2(v0.z, v0.w), pk2(v1.x, v1.y), pk2(v1.z, v1.w)};
      *(uint4*)&h_lds[hb * 264 + hc * 8] = pk;
    }
    __syncthreads();
  }
}

// ---------------- K3: out = sigmoid(hs @ Wm^T @ Wf^T + const), partial sums -
__global__ __launch_bounds__(256) void k_out(const float* __restrict__ hs,
                                             const float* __restrict__ Wm,
                                             const float* __restrict__ bm,
                                             const float* __restrict__ wf_g,
                                             const float* __restrict__ bf_g,
                                             float* __restrict__ partials) {
  const int ttile = blockIdx.x, b = blockIdx.y;
  const int tid = threadIdx.x;
  __shared__ float hsl[64 * 276];
  __shared__ float wml[64 * 276];
  __shared__ float s_lds[64];
  __shared__ float credv[4];
  __shared__ float cterm_s;
  if (tid < 64) s_lds[tid] = 0.f;
  {
    const int r = tid >> 2, c0 = (tid & 3) * 64;
    const float* src = hs + (size_t)(ttile * 64 + r + 1) * (BATCH * HDIM) +
                       (size_t)b * HDIM + c0;
#pragma unroll
    for (int s = 0; s < 64; s += 4)
      *(float4*)&hsl[r * 276 + c0 + s] = *(const float4*)(src + s);
  }
  const int lane = tid & 63;
  const int tt = tid >> 4, tj = tid & 15;
  for (int jt = 0; jt < 4; ++jt) {
    __syncthreads();
    {
      const int r = tid >> 2, c0 = (tid & 3) * 64;
      const float* src = Wm + (size_t)(jt * 64 + r) * HDIM + c0;
#pragma unroll
      for (int s = 0; s < 64; s += 4)
        *(float4*)&wml[r * 276 + c0 + s] = *(const float4*)(src + s);
    }
    __syncthreads();
    float accv[4][4] = {{0.f}};
    for (int k4 = 0; k4 < 64; ++k4) {
      float4 av[4], bv[4];
#pragma unroll
      for (int i = 0; i < 4; ++i) av[i] = *(const float4*)&hsl[(tt * 4 + i) * 276 + k4 * 4];
#pragma unroll
      for (int j = 0; j < 4; ++j) bv[j] = *(const float4*)&wml[(tj * 4 + j) * 276 + k4 * 4];
#pragma unroll
      for (int i = 0; i < 4; ++i)
#pragma unroll
        for (int j = 0; j < 4; ++j)
          accv[i][j] += av[i].x * bv[j].x + av[i].y * bv[j].y +
                        av[i].z * bv[j].z + av[i].w * bv[j].w;
    }
    float wfv[4];
#pragma unroll
    for (int j = 0; j < 4; ++j) wfv[j] = wf_g[jt * 64 + tj * 4 + j];
#pragma unroll
    for (int i = 0; i < 4; ++i) {
      float s = accv[i][0] * wfv[0] + accv[i][1] * wfv[1] +
                accv[i][2] * wfv[2] + accv[i][3] * wfv[3];
      s += __shfl_xor(s, 1); s += __shfl_xor(s, 2);
      s += __shfl_xor(s, 4); s += __shfl_xor(s, 8);
      if ((lane & 15) == 0) s_lds[tt * 4 + i] += s;
    }
  }
  __syncthreads();
  {
    float cp = bm[tid] * wf_g[tid];  // constant term sum(bm*Wf)
    cp += __shfl_xor(cp, 1); cp += __shfl_xor(cp, 2); cp += __shfl_xor(cp, 4);
    cp += __shfl_xor(cp, 8); cp += __shfl_xor(cp, 16); cp += __shfl_xor(cp, 32);
    if (lane == 0) credv[tid >> 6] = cp;
  }
  __syncthreads();
  if (tid == 0) cterm_s = credv[0] + credv[1] + credv[2] + credv[3] + bf_g[0];
  __syncthreads();
  if (tid < 64) {
    float sg = __builtin_amdgcn_rcpf(1.f + __expf(-(s_lds[tid] + cterm_s)));
    sg += __shfl_xor(sg, 1); sg += __shfl_xor(sg, 2); sg += __shfl_xor(sg, 4);
    sg += __shfl_xor(sg, 8); sg += __shfl_xor(sg, 16); sg += __shfl_xor(sg, 32);
    if (tid == 0) partials[b * 8 + ttile] = sg;
  }
}

// ---------------- K4: mean over T ------------------------------------------
__global__ void k_mean(const float* __restrict__ partials, float* __restrict__ out) {
  const int b = threadIdx.x;
  if (b < 64) {
    float s = 0.f;
#pragma unroll
    for (int i = 0; i < 8; ++i) s += partials[b * 8 + i];
    out[b] = s * (1.f / 512.f);
  }
}

extern "C" void kernel_launch(void* const* d_in, const int* in_sizes, int n_in,
                              void* d_out, int out_size, void* d_ws, size_t ws_size,
                              hipStream_t stream) {
  (void)in_sizes; (void)n_in; (void)out_size; (void)ws_size;
  const int* x = (const int*)d_in[0];
  const float* emb = (const float*)d_in[1];
  const float* Wih = (const float*)d_in[2];
  const float* Whh = (const float*)d_in[3];
  const float* bih = (const float*)d_in[4];
  const float* bhh = (const float*)d_in[5];
  const float* Wm  = (const float*)d_in[6];
  const float* bm  = (const float*)d_in[7];
  const float* Wf  = (const float*)d_in[8];
  const float* bf  = (const float*)d_in[9];
  float* out = (float*)d_out;
  char* ws = (char*)d_ws;
  const size_t gx_bytes = (size_t)TSTEPS * BATCH * G4H * 2;       // 67,108,864
  const size_t hs_bytes = (size_t)(TSTEPS + 1) * BATCH * HDIM * 4;// 33,619,968
  unsigned short* gx = (unsigned short*)ws;
  float* hs = (float*)(ws + gx_bytes);
  float* partials = (float*)(ws + gx_bytes + hs_bytes);
  unsigned* cnt = (unsigned*)(ws + gx_bytes + hs_bytes + 4096);
  hipMemsetAsync(hs, 0, (size_t)BATCH * HDIM * 4, stream);  // h^(0) = 0
  hipMemsetAsync(cnt, 0, 256, stream);                      // group counters
  k_gx<<<dim3(512, 16), 256, 0, stream>>>(x, emb, Wih, bih, gx);
  k_rec<<<32, 512, 0, stream>>>(gx, Whh, bhh, hs, cnt, out);
  k_out<<<dim3(8, 64), 256, 0, stream>>>(hs, Wm, bm, Wf, bf, partials);
  k_mean<<<1, 64, 0, stream>>>(partials, out);
}

// Round 2
// 1886.743 us; speedup vs baseline: 3.0665x; 3.0665x over previous
//
#include <hip/hip_runtime.h>

// SentimentLSTM: B=64, T=512, E=128, H=256, V=100000, O=1
// outputs: sig_out[64], hT[1,64,256], cT[1,64,256] -> 32832 f32
//
// ws layout:
//   gx    bf16 [T][B][4H]      67,108,864 B
//   hs    f32  [T][B][H]       33,554,432 B   (row t = h_{t+1})
//   hx    bf16 [2][B][H]           65,536 B   (step-parity exchange buffer)
//   flags u32  [4][16]                256 B   (padded to one line per group)
//   weff  f32  [257]                1,028 B
// total ~100.73 MB

#define BATCH 64
#define TSTEPS 512
#define EDIM 128
#define HDIM 256
#define G4H 1024

typedef short bf16x8 __attribute__((ext_vector_type(8)));
typedef short bf16x4 __attribute__((ext_vector_type(4)));
typedef float f32x4 __attribute__((ext_vector_type(4)));

__device__ __forceinline__ unsigned short f2bf(float f) {
  unsigned u = __builtin_bit_cast(unsigned, f);
  return (unsigned short)((u + 0x7fffu + ((u >> 16) & 1u)) >> 16);
}
__device__ __forceinline__ float bf2f(unsigned short h) {
  unsigned u = ((unsigned)h) << 16;
  return __builtin_bit_cast(float, u);
}
__device__ __forceinline__ unsigned pk2(float a, float b) {
  return (unsigned)f2bf(a) | ((unsigned)f2bf(b) << 16);
}
__device__ __forceinline__ float fsig(float x) {
  return __builtin_amdgcn_rcpf(1.f + __expf(-x));
}
__device__ __forceinline__ float ftanh(float x) {
  return 1.f - 2.f * __builtin_amdgcn_rcpf(__expf(2.f * x) + 1.f);
}
// Load an 8-elem bf16 fragment: elems 0-3 at k0, elems 4-7 at k0+16.
// Same recipe used for A and B everywhere -> k-permutation cancels.
__device__ __forceinline__ bf16x8 ldfrag(const unsigned short* p) {
  bf16x4 a = *(const bf16x4*)p;
  bf16x4 b = *(const bf16x4*)(p + 16);
  return __builtin_shufflevector(a, b, 0, 1, 2, 3, 4, 5, 6, 7);
}

// ---------------- K1: gx[t][b][g] = emb[x[b,t]] @ W_ih^T + b_ih  (bf16 out) --
__global__ __launch_bounds__(256) void k_gx(const int* __restrict__ x,
                                            const float* __restrict__ emb,
                                            const float* __restrict__ Wih,
                                            const float* __restrict__ bih,
                                            unsigned short* __restrict__ gx) {
  const int t = blockIdx.x;        // 0..511 (one t = all 64 batches = M tile)
  const int g0 = blockIdx.y * 64;  // gate-col tile
  const int tid = threadIdx.x;
  __shared__ unsigned short Al[64 * 136];  // emb rows, bf16, padded stride
  __shared__ unsigned short Bl[64 * 136];  // W_ih rows, bf16
  __shared__ int tok[64];
  if (tid < 64) tok[tid] = x[tid * TSTEPS + t];  // x[b][t]
  __syncthreads();
  {
    const int r = tid >> 2, c0 = (tid & 3) * 32;
    const float* asrc = emb + (size_t)tok[r] * EDIM + c0;
    const float* bsrc = Wih + (size_t)(g0 + r) * EDIM + c0;
#pragma unroll
    for (int s = 0; s < 32; s += 8) {
      float4 a0 = *(const float4*)(asrc + s);
      float4 a1 = *(const float4*)(asrc + s + 4);
      uint4 pa = {pk2(a0.x, a0.y), pk2(a0.z, a0.w), pk2(a1.x, a1.y), pk2(a1.z, a1.w)};
      *(uint4*)&Al[r * 136 + c0 + s] = pa;
      float4 b0 = *(const float4*)(bsrc + s);
      float4 b1 = *(const float4*)(bsrc + s + 4);
      uint4 pb = {pk2(b0.x, b0.y), pk2(b0.z, b0.w), pk2(b1.x, b1.y), pk2(b1.z, b1.w)};
      *(uint4*)&Bl[r * 136 + c0 + s] = pb;
    }
  }
  __syncthreads();
  const int lane = tid & 63, w = tid >> 6;
  const int lo = lane & 15, hi = lane >> 4;
  const int mb = (w & 1) * 32, nb = (w >> 1) * 32;
  f32x4 acc[2][2];
#pragma unroll
  for (int j = 0; j < 2; ++j) {
    float bv = bih[g0 + nb + j * 16 + lo];
    acc[0][j] = (f32x4){bv, bv, bv, bv};
    acc[1][j] = acc[0][j];
  }
#pragma unroll
  for (int kk = 0; kk < 4; ++kk) {
    bf16x8 af0 = ldfrag(&Al[(mb + lo) * 136 + kk * 32 + hi * 4]);
    bf16x8 af1 = ldfrag(&Al[(mb + 16 + lo) * 136 + kk * 32 + hi * 4]);
    bf16x8 bf0 = ldfrag(&Bl[(nb + lo) * 136 + kk * 32 + hi * 4]);
    bf16x8 bf1 = ldfrag(&Bl[(nb + 16 + lo) * 136 + kk * 32 + hi * 4]);
    acc[0][0] = __builtin_amdgcn_mfma_f32_16x16x32_bf16(af0, bf0, acc[0][0], 0, 0, 0);
    acc[0][1] = __builtin_amdgcn_mfma_f32_16x16x32_bf16(af0, bf1, acc[0][1], 0, 0, 0);
    acc[1][0] = __builtin_amdgcn_mfma_f32_16x16x32_bf16(af1, bf0, acc[1][0], 0, 0, 0);
    acc[1][1] = __builtin_amdgcn_mfma_f32_16x16x32_bf16(af1, bf1, acc[1][1], 0, 0, 0);
  }
#pragma unroll
  for (int i = 0; i < 2; ++i)
#pragma unroll
    for (int j = 0; j < 2; ++j)
#pragma unroll
      for (int r = 0; r < 4; ++r) {
        int m = mb + i * 16 + hi * 4 + r;     // batch (C row)
        int col = g0 + nb + j * 16 + lo;      // gate col (C col)
        gx[(size_t)(t * BATCH + m) * G4H + col] = f2bf(acc[i][j][r]);
      }
}

// ---------------- K2: the LSTM recurrence ----------------------------------
// 4 groups x 16 batches; each group = 8 blocks, block owns 32 hidden units
// (128 W_hh rows) held as persistent bf16 MFMA B-fragments in VGPRs.
// Cross-block exchange: packed-bf16 h through the coherent point (relaxed
// agent-scope atomics = global ops with sc1, no L2 fences), parity
// double-buffer, per-producer flags. NO __threadfence anywhere.
__global__ __launch_bounds__(512) void k_rec(const unsigned short* __restrict__ gx,
                                             const float* __restrict__ Whh,
                                             const float* __restrict__ bhh,
                                             unsigned* __restrict__ hx,     // [2][64][128] u32
                                             unsigned* __restrict__ flags,  // [4][16]
                                             float* __restrict__ hs,        // [512][64][256]
                                             float* __restrict__ out) {
  const int tid = threadIdx.x;
  const int grp = blockIdx.x >> 3, p = blockIdx.x & 7;
  const int b0 = grp * 16, j0 = p * 32;
  const int lane = tid & 63, w = tid >> 6;
  const int lo = lane & 15, hi = lane >> 4;
  const int gate = w >> 1, jw = (w & 1) * 16;
  const int grow = gate * HDIM + j0 + jw + lo;  // this lane's W_hh row (= C col)
  __shared__ unsigned short h_lds[16 * 264];    // [16 batch][256 k] bf16, pad 8
  __shared__ unsigned short gx_lds[2][16 * 128];// dbuf [16 batch][4g x 32u] bf16
  __shared__ float g_lds[4][32][17];            // [gate][unit][batch] pad
  // persistent W fragments (one-time load, f32 -> bf16)
  bf16x8 wf[8];
#pragma unroll
  for (int kk = 0; kk < 8; ++kk) {
    const float* wsrc = Whh + (size_t)grow * HDIM + kk * 32 + hi * 4;
    float4 v0 = *(const float4*)wsrc;
    float4 v1 = *(const float4*)(wsrc + 16);
    bf16x8 f;
    f[0] = (short)f2bf(v0.x); f[1] = (short)f2bf(v0.y);
    f[2] = (short)f2bf(v0.z); f[3] = (short)f2bf(v0.w);
    f[4] = (short)f2bf(v1.x); f[5] = (short)f2bf(v1.y);
    f[6] = (short)f2bf(v1.z); f[7] = (short)f2bf(v1.w);
    wf[kk] = f;
  }
  const float bhv = bhh[grow];
  const int ub = tid >> 5, uu = tid & 31;  // update-phase (batch, unit)
  float c_reg = 0.f;
  // initial stage: gx[0]; h^(0) = 0 directly in LDS
  {
    if (tid < 256) {
      const int fb = tid >> 4, fg = (tid >> 2) & 3, fq = tid & 3;
      uint4 v = *(const uint4*)(gx + (size_t)(b0 + fb) * G4H + fg * HDIM + j0 + fq * 8);
      *(uint4*)&gx_lds[0][fb * 128 + fg * 32 + fq * 8] = v;
    }
    const int hb = tid >> 5, hc = tid & 31;
    *(uint4*)&h_lds[hb * 264 + hc * 8] = (uint4){0u, 0u, 0u, 0u};
  }
  __syncthreads();
  unsigned* const myflag = &flags[grp * 16 + p];
  unsigned* const grpflags = &flags[grp * 16];
  for (int t = 0; t < TSTEPS; ++t) {
    const int pbuf = t & 1;
    // C init = gx + b_hh  (C map: row=batch=(hi*4+r), col=this lane's unit)
    f32x4 acc;
#pragma unroll
    for (int r = 0; r < 4; ++r)
      acc[r] = bf2f(gx_lds[pbuf][(hi * 4 + r) * 128 + gate * 32 + jw + lo]) + bhv;
    // h @ W^T : A row = batch = lo, same k recipe as wf
#pragma unroll
    for (int kk = 0; kk < 8; ++kk) {
      bf16x8 af = ldfrag(&h_lds[lo * 264 + kk * 32 + hi * 4]);
      acc = __builtin_amdgcn_mfma_f32_16x16x32_bf16(af, wf[kk], acc, 0, 0, 0);
    }
#pragma unroll
    for (int r = 0; r < 4; ++r) g_lds[gate][jw + lo][hi * 4 + r] = acc[r];
    __syncthreads();
    // prefetch next gx tile into registers (hidden under update phase)
    uint4 gpre;
    const bool dopf = (t < TSTEPS - 1) && (tid < 256);
    if (dopf) {
      const int fb = tid >> 4, fg = (tid >> 2) & 3, fq = tid & 3;
      gpre = *(const uint4*)(gx + (size_t)(t + 1) * (BATCH * G4H) +
                             (size_t)(b0 + fb) * G4H + fg * HDIM + j0 + fq * 8);
    }
    // cell update (torch gate order i,f,g,o)
    float iv = fsig(g_lds[0][uu][ub]);
    float fv = fsig(g_lds[1][uu][ub]);
    float gv = ftanh(g_lds[2][uu][ub]);
    float ov = fsig(g_lds[3][uu][ub]);
    c_reg = fv * c_reg + iv * gv;
    float hval = ov * ftanh(c_reg);
    hs[(size_t)t * (BATCH * HDIM) + (size_t)(b0 + ub) * HDIM + j0 + uu] = hval;
    if (t == TSTEPS - 1) {
      out[64 + (b0 + ub) * HDIM + j0 + uu] = hval;                 // hT
      out[64 + BATCH * HDIM + (b0 + ub) * HDIM + j0 + uu] = c_reg; // cT
    }
    // exchange store: packed bf16 pair through the coherent point (sc1)
    const int par = (t + 1) & 1;
    {
      float hpart = __shfl_xor(hval, 1);
      if (!(lane & 1)) {
        unsigned pkv = (unsigned)f2bf(hval) | ((unsigned)f2bf(hpart) << 16);
        __hip_atomic_store(&hx[par * 8192 + (b0 + ub) * 128 + ((j0 + uu) >> 1)],
                           pkv, __ATOMIC_RELAXED, __HIP_MEMORY_SCOPE_AGENT);
      }
    }
    if (dopf) {
      const int fb = tid >> 4, fg = (tid >> 2) & 3, fq = tid & 3;
      *(uint4*)&gx_lds[pbuf ^ 1][fb * 128 + fg * 32 + fq * 8] = gpre;
    }
    if (t == TSTEPS - 1) break;
    // per-wave: my hx stores have reached the coherent point
    asm volatile("s_waitcnt vmcnt(0)" ::: "memory");
    __syncthreads();  // whole block's stores acked
    const unsigned tgt = (unsigned)(t + 1);
    if (tid == 0)
      __hip_atomic_store(myflag, tgt, __ATOMIC_RELAXED, __HIP_MEMORY_SCOPE_AGENT);
    if (w == 0) {  // lanes 0..7 poll the 8 producer flags (one cache line)
      unsigned v = tgt;
      do {
        if (lane < 8)
          v = __hip_atomic_load(&grpflags[lane], __ATOMIC_RELAXED,
                                __HIP_MEMORY_SCOPE_AGENT);
      } while (__any(v < tgt));
    }
    __syncthreads();
    // reload full group h (bf16 pairs) from coherent point into LDS
#pragma unroll
    for (int i = 0; i < 4; ++i) {
      const int idx = tid + i * 512;  // 0..2047 u32 slots
      const int b = idx >> 7, u2 = idx & 127;
      unsigned v = __hip_atomic_load(&hx[par * 8192 + (b0 + b) * 128 + u2],
                                     __ATOMIC_RELAXED, __HIP_MEMORY_SCOPE_AGENT);
      *(unsigned*)&h_lds[b * 264 + u2 * 2] = v;
    }
    __syncthreads();
  }
}

// ---------------- K3: w_eff[k] = sum_j Wf[j]*Wm[j][k]; weff[256] = bm.Wf+bf --
__global__ __launch_bounds__(256) void k_weff(const float* __restrict__ Wm,
                                              const float* __restrict__ bm,
                                              const float* __restrict__ Wf,
                                              const float* __restrict__ bfb,
                                              float* __restrict__ weff) {
  const int k = threadIdx.x;
  __shared__ float red[256];
  float acc = 0.f;
#pragma unroll 8
  for (int j = 0; j < 256; ++j) acc += Wf[j] * Wm[j * 256 + k];
  weff[k] = acc;
  red[k] = bm[k] * Wf[k];
  __syncthreads();
  for (int s = 128; s > 0; s >>= 1) {
    if (k < s) red[k] += red[k + s];
    __syncthreads();
  }
  if (k == 0) weff[256] = red[0] + bfb[0];
}

// ---------------- K4: sig_out[b] = mean_t sigmoid(h_t . weff + c0) ----------
__global__ __launch_bounds__(256) void k_sig(const float* __restrict__ hs,
                                             const float* __restrict__ weff,
                                             float* __restrict__ out) {
  const int b = blockIdx.x;
  const int tid = threadIdx.x, lane = tid & 63, w = tid >> 6;
  __shared__ float wlds[4];
  const float4 w4 = *(const float4*)&weff[lane * 4];
  const float c0 = weff[256];
  float acc = 0.f;
  for (int row = w; row < TSTEPS; row += 4) {
    float4 h4 = *(const float4*)&hs[(size_t)row * (BATCH * HDIM) + b * HDIM + lane * 4];
    float s = h4.x * w4.x + h4.y * w4.y + h4.z * w4.z + h4.w * w4.w;
    s += __shfl_xor(s, 1);  s += __shfl_xor(s, 2);  s += __shfl_xor(s, 4);
    s += __shfl_xor(s, 8);  s += __shfl_xor(s, 16); s += __shfl_xor(s, 32);
    acc += fsig(s + c0);
  }
  if (lane == 0) wlds[w] = acc;
  __syncthreads();
  if (tid == 0) out[b] = (wlds[0] + wlds[1] + wlds[2] + wlds[3]) * (1.f / 512.f);
}

extern "C" void kernel_launch(void* const* d_in, const int* in_sizes, int n_in,
                              void* d_out, int out_size, void* d_ws, size_t ws_size,
                              hipStream_t stream) {
  (void)in_sizes; (void)n_in; (void)out_size; (void)ws_size;
  const int* x = (const int*)d_in[0];
  const float* emb = (const float*)d_in[1];
  const float* Wih = (const float*)d_in[2];
  const float* Whh = (const float*)d_in[3];
  const float* bih = (const float*)d_in[4];
  const float* bhh = (const float*)d_in[5];
  const float* Wm  = (const float*)d_in[6];
  const float* bm  = (const float*)d_in[7];
  const float* Wf  = (const float*)d_in[8];
  const float* bf  = (const float*)d_in[9];
  float* out = (float*)d_out;
  char* ws = (char*)d_ws;
  const size_t gx_bytes = (size_t)TSTEPS * BATCH * G4H * 2;        // 67,108,864
  const size_t hs_bytes = (size_t)TSTEPS * BATCH * HDIM * 4;       // 33,554,432
  const size_t hx_bytes = (size_t)2 * BATCH * HDIM * 2;            // 65,536
  unsigned short* gx = (unsigned short*)ws;
  float* hs = (float*)(ws + gx_bytes);
  unsigned* hx = (unsigned*)(ws + gx_bytes + hs_bytes);
  unsigned* flags = (unsigned*)(ws + gx_bytes + hs_bytes + hx_bytes);
  float* weff = (float*)(ws + gx_bytes + hs_bytes + hx_bytes + 512);
  hipMemsetAsync(flags, 0, 256, stream);  // per-launch flag reset (in-graph ok)
  k_gx<<<dim3(512, 16), 256, 0, stream>>>(x, emb, Wih, bih, gx);
  k_weff<<<1, 256, 0, stream>>>(Wm, bm, Wf, bf, weff);
  k_rec<<<32, 512, 0, stream>>>(gx, Whh, bhh, hx, flags, hs, out);
  k_sig<<<64, 256, 0, stream>>>(hs, weff, out);
}